// Round 2
// baseline (2823.738 us; speedup 1.0000x reference)
//
#include <hip/hip_runtime.h>
#include <hip/hip_bf16.h>

#define DEVI __device__ __forceinline__

DEVI float bf2f(__hip_bfloat16 v) { return __bfloat162float(v); }

// flag-dependent element load/store: isf32 selects float32 vs bf16 view
DEVI float ldin(const void* p, size_t i, int isf32) {
    return isf32 ? ((const float*)p)[i] : bf2f(((const __hip_bfloat16*)p)[i]);
}
DEVI void stio(void* p, size_t i, float v, int isf32) {
    if (isf32) ((float*)p)[i] = v;
    else ((__hip_bfloat16*)p)[i] = __float2bfloat16(v);
}

// ACT: 0 none, 1 leaky(0.1), 2 leaky(0.01), 3 prelu(alpha)
template <int ACT>
DEVI float act_fn(float v, float alpha) {
    if (ACT == 1) return v >= 0.f ? v : 0.1f * v;
    if (ACT == 2) return v >= 0.f ? v : 0.01f * v;
    if (ACT == 3) return v >= 0.f ? v : alpha * v;
    return v;
}

DEVI float waveRed(float v) {
#pragma unroll
    for (int o = 32; o > 0; o >>= 1) v += __shfl_down(v, o);
    return v;
}

DEVI float blockRed(float v) {
    __shared__ float sm[16];
    int lane = threadIdx.x & 63, w = threadIdx.x >> 6;
    v = waveRed(v);
    if (lane == 0) sm[w] = v;
    __syncthreads();
    if (w == 0) {
        int nw = (blockDim.x + 63) >> 6;
        v = (lane < nw) ? sm[lane] : 0.f;
        v = waveRed(v);
    }
    return v;  // valid on thread 0
}

// ---------------- dtype probe ----------------
// Interpret first 4096 elements of x as bf16. Genuine bf16 N(0,1): ~0% fail.
// float32 data read as bf16: even elements are mantissa fragments -> ~45% fail.
__global__ void probe_k(const void* __restrict__ x, int* __restrict__ flag) {
    __shared__ int sfails;
    int t = threadIdx.x;
    if (t == 0) sfails = 0;
    __syncthreads();
    const __hip_bfloat16* xb = (const __hip_bfloat16*)x;
    int my = 0;
    for (int i = t; i < 4096; i += 256) {
        float v = bf2f(xb[i]);
        float a = fabsf(v);
        if (!(a <= 64.f) || (v != 0.f && a < 1e-6f)) my++;  // !(a<=64) catches NaN too
    }
    atomicAdd(&sfails, my);
    __syncthreads();
    if (t == 0) flag[0] = (sfails > 409) ? 1 : 0;  // >10% fail => data is float32
}

// ---------------- tiled f32 GEMM: C = act(A[MxK] @ W[KxN] + b) ----------------
// BM=BN=64, BK=16, 256 threads, 4x4 per thread. LDA=68 padding avoids conflicts.
#define GBM 64
#define GBN 64
#define GBK 16
#define GLDA 68

// AMODE: 0 = A follows dtype flag (model input), 1 = A is f32 workspace
// OMODE: 0 = out is f32 workspace, 1 = out follows dtype flag (d_out)
template <int AMODE, int ACT, int OMODE>
__global__ __launch_bounds__(256) void gemm_k(
    const void* __restrict__ A, const void* __restrict__ W,
    const void* __restrict__ bias, void* __restrict__ outp, size_t ooff,
    const int* __restrict__ flagp, int M, int K, int Nc) {
    __shared__ float As[GBK * GLDA];
    __shared__ float Bs[GBK * GLDA];
    const int f32 = flagp[0];
    int tid = threadIdx.x;
    int tx = tid & 15, ty = tid >> 4;
    int rowBase = blockIdx.x * GBM;
    int colBase = blockIdx.y * GBN;
    float acc[4][4] = {};
    for (int k0 = 0; k0 < K; k0 += GBK) {
#pragma unroll
        for (int i = 0; i < 4; i++) {
            int idx = tid + 256 * i;
            int rl = idx >> 4, kk = idx & 15;
            int gr = rowBase + rl;
            float v = 0.f;
            if (gr < M) {
                size_t ai = (size_t)gr * K + k0 + kk;
                v = (AMODE == 1) ? ((const float*)A)[ai] : ldin(A, ai, f32);
            }
            As[kk * GLDA + rl] = v;
        }
#pragma unroll
        for (int i = 0; i < 4; i++) {
            int idx = tid + 256 * i;
            int kk = idx >> 6, nn = idx & 63;
            int gc = colBase + nn;
            float v = 0.f;
            if (gc < Nc) v = ldin(W, (size_t)(k0 + kk) * Nc + gc, f32);
            Bs[kk * GLDA + nn] = v;
        }
        __syncthreads();
#pragma unroll
        for (int k = 0; k < GBK; k++) {
            float a[4], b[4];
#pragma unroll
            for (int i = 0; i < 4; i++) a[i] = As[k * GLDA + ty + 16 * i];
#pragma unroll
            for (int j = 0; j < 4; j++) b[j] = Bs[k * GLDA + tx + 16 * j];
#pragma unroll
            for (int i = 0; i < 4; i++)
#pragma unroll
                for (int j = 0; j < 4; j++) acc[i][j] += a[i] * b[j];
        }
        __syncthreads();
    }
#pragma unroll
    for (int i = 0; i < 4; i++) {
        int gr = rowBase + ty + 16 * i;
        if (gr >= M) continue;
#pragma unroll
        for (int j = 0; j < 4; j++) {
            int gc = colBase + tx + 16 * j;
            if (gc >= Nc) continue;
            float v = acc[i][j] + ldin(bias, gc, f32);
            v = act_fn<ACT>(v, 0.f);
            size_t oi = (size_t)gr * Nc + gc;
            if (OMODE == 1)
                stio(outp, ooff + oi, v, f32);
            else
                ((float*)outp)[oi] = v;
        }
    }
}

// ---------------- CSR build ----------------
__global__ void count_k(const int* __restrict__ rows, int* __restrict__ counts, int nnz) {
    int i = blockIdx.x * blockDim.x + threadIdx.x;
    if (i < nnz) atomicAdd(&counts[rows[i]], 1);
}

__global__ __launch_bounds__(1024) void scan_local_k(const int* __restrict__ counts,
                                                     int* __restrict__ offs,
                                                     int* __restrict__ bsums, int n) {
    __shared__ int sm[1024];
    int t = threadIdx.x;
    int g = blockIdx.x * 1024 + t;
    int v = (g < n) ? counts[g] : 0;
    sm[t] = v;
    __syncthreads();
    for (int d = 1; d < 1024; d <<= 1) {
        int add = (t >= d) ? sm[t - d] : 0;
        __syncthreads();
        sm[t] += add;
        __syncthreads();
    }
    if (g < n) offs[g] = sm[t] - v;  // exclusive
    if (t == 1023) bsums[blockIdx.x] = sm[t];
}

__global__ void scan_bsums_k(int* bsums, int nb) {
    if (threadIdx.x == 0 && blockIdx.x == 0) {
        int acc = 0;
        for (int i = 0; i < nb; i++) {
            int v = bsums[i];
            bsums[i] = acc;
            acc += v;
        }
    }
}

__global__ void scan_add_k(int* __restrict__ offs, const int* __restrict__ bsums, int n, int nnz) {
    int g = blockIdx.x * blockDim.x + threadIdx.x;
    if (g < n) offs[g] += bsums[g >> 10];
    if (g == 0) offs[n] = nnz;
}

__global__ void fill_k(const int* __restrict__ rows, const int* __restrict__ cols,
                       const void* __restrict__ vals, const int* __restrict__ offs,
                       int* __restrict__ cursor, int* __restrict__ cols_s,
                       float* __restrict__ vals_s, const int* __restrict__ flagp, int nnz) {
    int e = blockIdx.x * blockDim.x + threadIdx.x;
    if (e < nnz) {
        int r = rows[e];
        int pos = offs[r] + atomicAdd(&cursor[r], 1);
        cols_s[pos] = cols[e];
        vals_s[pos] = ldin(vals, e, flagp[0]);
    }
}

// ---------------- SpMM (CSR, one block per dest row) ----------------
template <int ACT>
__global__ __launch_bounds__(256) void spmm_k(
    const int* __restrict__ offs, const int* __restrict__ cols_s,
    const float* __restrict__ vals_s, const int* __restrict__ perm,
    const void* __restrict__ alpha_p, const int* __restrict__ flagp,
    const float* __restrict__ Min, float* __restrict__ out, int F) {
    int row = blockIdx.x;
    int f0 = threadIdx.x;
    float alpha = (ACT == 3) ? ldin(alpha_p, 0, flagp[0]) : 0.f;
    int s = offs[row], e = offs[row + 1];
    float acc0 = 0.f, acc1 = 0.f;
    int f1 = f0 + 256;
    bool has1 = f1 < F;
    for (int i = s; i < e; i++) {
        int c = cols_s[i];
        if (perm) c = perm[c];
        float v = vals_s[i];
        const float* src = Min + (size_t)c * F;
        acc0 += v * src[f0];
        if (has1) acc1 += v * src[f1];
    }
    out[(size_t)row * F + f0] = act_fn<ACT>(acc0, alpha);
    if (has1) out[(size_t)row * F + f1] = act_fn<ACT>(acc1, alpha);
}

// ---------------- BatchNorm ----------------
__global__ __launch_bounds__(256) void bn_stats_k(const float* __restrict__ h,
                                                  float* __restrict__ sum,
                                                  float* __restrict__ sumsq, int nrows, int rpb) {
    int c = threadIdx.x;  // blockDim == HID
    int rs = blockIdx.x * rpb;
    int re = min(rs + rpb, nrows);
    float s = 0.f, s2 = 0.f;
    int H = blockDim.x;
    for (int r = rs; r < re; r++) {
        float v = h[(size_t)r * H + c];
        s += v;
        s2 += v * v;
    }
    atomicAdd(&sum[c], s);
    atomicAdd(&sumsq[c], s2);
}

__global__ void bn_final_k(const float* __restrict__ sum, const float* __restrict__ sumsq,
                           const void* __restrict__ gamma, const void* __restrict__ beta,
                           float* __restrict__ scale, float* __restrict__ shift,
                           const int* __restrict__ flagp, int nrows) {
    int c = threadIdx.x;
    int f32 = flagp[0];
    float mu = sum[c] / nrows;
    float var = sumsq[c] / nrows - mu * mu;
    float sc = ldin(gamma, c, f32) * rsqrtf(var + 1e-5f);
    scale[c] = sc;
    shift[c] = ldin(beta, c, f32) - mu * sc;
}

__global__ void bn_apply_k(float* __restrict__ h, const float* __restrict__ scale,
                           const float* __restrict__ shift) {
    int c = threadIdx.x;
    int H = blockDim.x;
    size_t i = (size_t)blockIdx.x * H + c;
    h[i] = h[i] * scale[c] + shift[c];
}

// ---------------- agg scatter + MSE ----------------
__global__ void agg_k(const void* __restrict__ dout, const int* __restrict__ agg_rows,
                      const void* __restrict__ agg_vals, float* __restrict__ agg,
                      const int* __restrict__ flagp, int F) {
    int i = blockIdx.x;
    int f = threadIdx.x;
    int f32 = flagp[0];
    if (f < F) {
        int r = agg_rows[i];
        float v = ldin(agg_vals, i, f32);
        float xv = ldin(dout, (size_t)1 + (size_t)i * F + f, f32);
        atomicAdd(&agg[(size_t)r * F + f], v * xv);
    }
}

__global__ __launch_bounds__(256) void mse_k(const float* __restrict__ agg,
                                             const void* __restrict__ y,
                                             float* __restrict__ acc,
                                             const int* __restrict__ flagp, int n) {
    int f32 = flagp[0];
    float s = 0.f;
    for (int i = blockIdx.x * blockDim.x + threadIdx.x; i < n; i += gridDim.x * blockDim.x) {
        float d = agg[i] - ldin(y, i, f32);
        s += d * d;
    }
    s = blockRed(s);
    if (threadIdx.x == 0) atomicAdd(acc, s);
}

// ---------------- DGI reductions ----------------
__global__ __launch_bounds__(320) void colsum_k(const float* __restrict__ h,
                                                float* __restrict__ accum, int nrows, int F,
                                                int rpb) {
    int f = threadIdx.x;
    if (f >= F) return;
    int rs = blockIdx.x * rpb;
    int re = min(rs + rpb, nrows);
    float s = 0.f;
    for (int r = rs; r < re; r++) s += h[(size_t)r * F + f];
    atomicAdd(&accum[f], s);
}

__global__ __launch_bounds__(320) void cfinal_k(const float* __restrict__ accum,
                                                float* __restrict__ c, float* __restrict__ cnorm,
                                                int N, int F) {
    int f = threadIdx.x;
    float v = 0.f;
    if (f < F) {
        v = accum[f] / N;
        c[f] = v;
    }
    float s2 = blockRed(v * v);
    if (threadIdx.x == 0) cnorm[0] = sqrtf(s2);
}

// MODE 0: sum += cos ; MODE 1: sum += max(cos,0)
template <int MODE>
__global__ __launch_bounds__(256) void cos_k(const float* __restrict__ h,
                                             const float* __restrict__ c,
                                             const float* __restrict__ cnorm,
                                             float* __restrict__ acc, int N, int F) {
    int gw = (blockIdx.x * blockDim.x + threadIdx.x) >> 6;
    int lane = threadIdx.x & 63;
    int nw = (gridDim.x * blockDim.x) >> 6;
    float cn = cnorm[0];
    float s = 0.f;
    for (int row = gw; row < N; row += nw) {
        float dot = 0.f, nsq = 0.f;
        for (int f = lane; f < F; f += 64) {
            float v = h[(size_t)row * F + f];
            dot += v * c[f];
            nsq += v * v;
        }
#pragma unroll
        for (int o = 32; o > 0; o >>= 1) {
            dot += __shfl_down(dot, o);
            nsq += __shfl_down(nsq, o);
        }
        if (lane == 0) {
            float cosv = dot / fmaxf(sqrtf(nsq) * cn, 1e-8f);
            s += (MODE == 1) ? fmaxf(cosv, 0.f) : cosv;
        }
    }
    s = blockRed(s);
    if (threadIdx.x == 0) atomicAdd(acc, s);
}

__global__ void final_k(const float* __restrict__ lacc, void* __restrict__ dout,
                        const int* __restrict__ flagp, int SOUT, int N) {
    if (threadIdx.x == 0 && blockIdx.x == 0) {
        float loss = lacc[0] / SOUT + (1.f - lacc[1] / N) + lacc[2] / N;
        stio(dout, 0, loss, flagp[0]);
    }
}

// ---------------- launch ----------------
extern "C" void kernel_launch(void* const* d_in, const int* in_sizes, int n_in,
                              void* d_out, int out_size, void* d_ws, size_t ws_size,
                              hipStream_t stream) {
    const void* x = d_in[0];
    const void* y = d_in[1];
    const int* adj_rows = (const int*)d_in[2];
    const int* adj_cols = (const int*)d_in[3];
    const void* adj_vals = d_in[4];
    const int* agg_rows = (const int*)d_in[5];
    const void* agg_vals = d_in[6];
    const int* perm = (const int*)d_in[7];
    const void* mlp_W = d_in[8];
    const void* mlp_b = d_in[9];
    const void* bn_gamma = d_in[10];
    const void* bn_beta = d_in[11];
    const void* hg_W1 = d_in[12];
    const void* hg_b1 = d_in[13];
    const void* hg_W2 = d_in[14];
    const void* hg_b2 = d_in[15];
    const void* hg_prelu = d_in[16];
    const void* pred_W = d_in[17];
    const void* pred_b = d_in[18];
    const void* dgi_W = d_in[19];
    const void* dgi_b = d_in[20];
    const void* dgi_prelu = d_in[21];

    const int N = in_sizes[5];         // 50000
    const int NNZ = in_sizes[2];       // 800000
    const int F_IN = in_sizes[0] / N;  // 1024
    const int HID = in_sizes[9];       // 256
    const int OUT = in_sizes[18];      // 280
    const int S = in_sizes[1] / OUT;   // 5000

    // workspace carve-up
    char* w = (char*)d_ws;
    size_t off = 0;
    auto alloc = [&](size_t b) -> char* {
        char* p = w + off;
        off += (b + 255) & ~(size_t)255;
        return p;
    };
    float* buf0 = (float*)alloc((size_t)N * HID * 4);  // h0
    float* bufA = (float*)alloc((size_t)N * OUT * 4);  // GEMM outs
    float* bufB = (float*)alloc((size_t)N * OUT * 4);  // spmm outs
    float* aggb = (float*)alloc((size_t)S * OUT * 4);
    int* counts = (int*)alloc((size_t)N * 4);
    int* cursor = (int*)alloc((size_t)N * 4);
    int* offs = (int*)alloc((size_t)(N + 1) * 4);
    int nbscan = (N + 1023) / 1024;
    int* bsums = (int*)alloc((size_t)nbscan * 4);
    int* cols_s = (int*)alloc((size_t)NNZ * 4);
    float* vals_s = (float*)alloc((size_t)NNZ * 4);
    float* bn_sum = (float*)alloc((size_t)HID * 4);
    float* bn_sumsq = (float*)alloc((size_t)HID * 4);
    float* bn_scale = (float*)alloc((size_t)HID * 4);
    float* bn_shift = (float*)alloc((size_t)HID * 4);
    float* c_acc = (float*)alloc((size_t)OUT * 4);
    float* c_vec = (float*)alloc((size_t)OUT * 4);
    float* cnorm = (float*)alloc(4);
    float* lacc = (float*)alloc(16);
    int* dflag = (int*)alloc(16);

    // zero what accumulates
    hipMemsetAsync(counts, 0, (size_t)N * 4, stream);
    hipMemsetAsync(cursor, 0, (size_t)N * 4, stream);
    hipMemsetAsync(bn_sum, 0, (size_t)HID * 4, stream);
    hipMemsetAsync(bn_sumsq, 0, (size_t)HID * 4, stream);
    hipMemsetAsync(c_acc, 0, (size_t)OUT * 4, stream);
    hipMemsetAsync(lacc, 0, 16, stream);
    hipMemsetAsync(aggb, 0, (size_t)S * OUT * 4, stream);

    // dtype probe (writes dflag[0]: 1 = float32 inputs, 0 = bf16 inputs)
    probe_k<<<1, 256, 0, stream>>>(x, dflag);

    // CSR build (reused by all 4 spmms)
    count_k<<<(NNZ + 255) / 256, 256, 0, stream>>>(adj_rows, counts, NNZ);
    scan_local_k<<<nbscan, 1024, 0, stream>>>(counts, offs, bsums, N);
    scan_bsums_k<<<1, 64, 0, stream>>>(bsums, nbscan);
    scan_add_k<<<(N + 255) / 256, 256, 0, stream>>>(offs, bsums, N, NNZ);
    fill_k<<<(NNZ + 255) / 256, 256, 0, stream>>>(adj_rows, adj_cols, adj_vals, offs, cursor,
                                                  cols_s, vals_s, dflag, NNZ);

    // h0 = leaky(x @ mlp_W + b, 0.1)
    dim3 g1((N + GBM - 1) / GBM, (HID + GBN - 1) / GBN);
    gemm_k<0, 1, 0><<<g1, 256, 0, stream>>>(x, mlp_W, mlp_b, buf0, 0, dflag, N, F_IN, HID);
    // BatchNorm (training-mode batch stats)
    bn_stats_k<<<(N + 127) / 128, HID, 0, stream>>>(buf0, bn_sum, bn_sumsq, N, 128);
    bn_final_k<<<1, HID, 0, stream>>>(bn_sum, bn_sumsq, bn_gamma, bn_beta, bn_scale, bn_shift,
                                      dflag, N);
    bn_apply_k<<<N, HID, 0, stream>>>(buf0, bn_scale, bn_shift);

    // HGNN layer 1: spmm(h0 @ W1 + b1) -> prelu
    dim3 g2((N + GBM - 1) / GBM, (HID + GBN - 1) / GBN);
    gemm_k<1, 0, 0><<<g2, 256, 0, stream>>>(buf0, hg_W1, hg_b1, bufA, 0, dflag, N, HID, HID);
    spmm_k<3><<<N, 256, 0, stream>>>(offs, cols_s, vals_s, nullptr, hg_prelu, dflag, bufA, bufB,
                                     HID);
    // HGNN layer 2: spmm(t @ W2 + b2) -> leaky 0.01
    gemm_k<1, 0, 0><<<g2, 256, 0, stream>>>(bufB, hg_W2, hg_b2, bufA, 0, dflag, N, HID, HID);
    spmm_k<2><<<N, 256, 0, stream>>>(offs, cols_s, vals_s, nullptr, nullptr, dflag, bufA, bufB,
                                     HID);

    // x_prime = leaky(h @ pred_W + b, 0.01) -> d_out elements [1 ...]
    dim3 g3((N + GBM - 1) / GBM, (OUT + GBN - 1) / GBN);
    gemm_k<1, 2, 1><<<g3, 256, 0, stream>>>(bufB, pred_W, pred_b, d_out, 1, dflag, N, HID, OUT);
    // agg = segment_sum(agg_vals * x_prime); mse
    agg_k<<<N, 320, 0, stream>>>(d_out, agg_rows, agg_vals, aggb, dflag, OUT);
    mse_k<<<256, 256, 0, stream>>>(aggb, y, &lacc[0], dflag, S * OUT);

    // DGI: z1 = h0 @ dgi_W + b ; h1 = prelu(spmm(z1)) ; h2 = prelu(spmm(z1 via perm[col]))
    gemm_k<1, 0, 0><<<g3, 256, 0, stream>>>(buf0, dgi_W, dgi_b, bufA, 0, dflag, N, HID, OUT);
    spmm_k<3><<<N, 256, 0, stream>>>(offs, cols_s, vals_s, nullptr, dgi_prelu, dflag, bufA, bufB,
                                     OUT);
    colsum_k<<<(N + 127) / 128, 320, 0, stream>>>(bufB, c_acc, N, OUT, 128);
    cfinal_k<<<1, 320, 0, stream>>>(c_acc, c_vec, cnorm, N, OUT);
    cos_k<0><<<256, 256, 0, stream>>>(bufB, c_vec, cnorm, &lacc[1], N, OUT);
    spmm_k<3><<<N, 256, 0, stream>>>(offs, cols_s, vals_s, perm, dgi_prelu, dflag, bufA, bufB,
                                     OUT);
    cos_k<1><<<256, 256, 0, stream>>>(bufB, c_vec, cnorm, &lacc[2], N, OUT);

    final_k<<<1, 64, 0, stream>>>(lacc, d_out, dflag, S * OUT, N);
}

// Round 3
// 1769.979 us; speedup vs baseline: 1.5954x; 1.5954x over previous
//
#include <hip/hip_runtime.h>
#include <hip/hip_bf16.h>

#define DEVI __device__ __forceinline__

typedef __attribute__((ext_vector_type(8))) short short8;
typedef __attribute__((ext_vector_type(4))) float float4v;

DEVI float bf2f(__hip_bfloat16 v) { return __bfloat162float(v); }
DEVI float ldbs(const ushort* p, size_t i) { return bf2f(((const __hip_bfloat16*)p)[i]); }
DEVI ushort f2bs(float v) {
    __hip_bfloat16 h = __float2bfloat16(v);
    return *(ushort*)&h;
}

// flag-dependent element load/store: isf32 selects float32 vs bf16 view
DEVI float ldin(const void* p, size_t i, int isf32) {
    return isf32 ? ((const float*)p)[i] : bf2f(((const __hip_bfloat16*)p)[i]);
}
DEVI void stio(void* p, size_t i, float v, int isf32) {
    if (isf32) ((float*)p)[i] = v;
    else ((ushort*)p)[i] = f2bs(v);
}

// ACT: 0 none, 1 leaky(0.1), 2 leaky(0.01), 3 prelu(alpha)
template <int ACT>
DEVI float act_fn(float v, float alpha) {
    if (ACT == 1) return v >= 0.f ? v : 0.1f * v;
    if (ACT == 2) return v >= 0.f ? v : 0.01f * v;
    if (ACT == 3) return v >= 0.f ? v : alpha * v;
    return v;
}

DEVI float waveRed(float v) {
#pragma unroll
    for (int o = 32; o > 0; o >>= 1) v += __shfl_down(v, o);
    return v;
}

DEVI float blockRed(float v) {
    __shared__ float sm[16];
    int lane = threadIdx.x & 63, w = threadIdx.x >> 6;
    v = waveRed(v);
    if (lane == 0) sm[w] = v;
    __syncthreads();
    if (w == 0) {
        int nw = (blockDim.x + 63) >> 6;
        v = (lane < nw) ? sm[lane] : 0.f;
        v = waveRed(v);
    }
    return v;  // valid on thread 0
}

// ---------------- dtype probe ----------------
__global__ void probe_k(const void* __restrict__ x, int* __restrict__ flag) {
    __shared__ int sfails;
    int t = threadIdx.x;
    if (t == 0) sfails = 0;
    __syncthreads();
    const __hip_bfloat16* xb = (const __hip_bfloat16*)x;
    int my = 0;
    for (int i = t; i < 4096; i += 256) {
        float v = bf2f(xb[i]);
        float a = fabsf(v);
        if (!(a <= 64.f) || (v != 0.f && a < 1e-6f)) my++;
    }
    atomicAdd(&sfails, my);
    __syncthreads();
    if (t == 0) flag[0] = (sfails > 409) ? 1 : 0;  // >10% fail => inputs are float32
}

// ---------------- weight transpose+convert: W[K][N] (flag dtype) -> Wt[N][K] bf16 --------
__global__ void cvt_wt_k(const void* __restrict__ in, ushort* __restrict__ out,
                         const int* __restrict__ flagp, int K, int Nc) {
    int f32 = flagp[0];
    int idx = blockIdx.x * blockDim.x + threadIdx.x;
    int total = K * Nc;
    if (idx < total) {
        int k = idx / Nc, n = idx % Nc;
        out[(size_t)n * K + k] = f2bs(ldin(in, idx, f32));
    }
}

// ---------------- MFMA bf16 GEMM ----------------
// C[M][Nc] = act(A[M][K] @ Bt[Nc][K]^T + bias)
// 128x128 tile, 256 threads (4 waves in 2x2), 16x16x32 MFMA, BK=32.
// LDS pitch 40 shorts (80B) -> conflict-free ds_read_b128 bank rotation.
// AMODE: 0 = A is flag-typed model input, 1 = A is bf16 workspace
// OMODE: 0 = out bf16 workspace, 1 = out is d_out (flag-typed), offset +1 elem
#define TP 40
template <int AMODE, int ACT, int OMODE>
__global__ __launch_bounds__(256) void mgemm_k(
    const void* __restrict__ A, const ushort* __restrict__ Bt,
    const void* __restrict__ bias, void* __restrict__ outp,
    const int* __restrict__ flagp, int M, int K, int Nc) {
    __shared__ short As[128 * TP];
    __shared__ short Bs[128 * TP];
    const int f32 = flagp[0];
    const int tid = threadIdx.x;
    const int lane = tid & 63;
    const int l15 = lane & 15;
    const int quad = lane >> 4;
    const int wid = tid >> 6;
    const int mW = (wid >> 1) * 64;
    const int nW = (wid & 1) * 64;
    const int mBase = blockIdx.x * 128;
    const int nBase = blockIdx.y * 128;

    float4v acc[4][4];
#pragma unroll
    for (int i = 0; i < 4; i++)
#pragma unroll
        for (int j = 0; j < 4; j++) acc[i][j] = (float4v){0.f, 0.f, 0.f, 0.f};

    for (int k0 = 0; k0 < K; k0 += 32) {
        // stage A tile (128 rows x 32 k) and B tile (128 cols x 32 k)
#pragma unroll
        for (int i = 0; i < 2; i++) {
            int chunk = i * 256 + tid;
            int row = chunk >> 2;
            int c = chunk & 3;
            short8 va = {0, 0, 0, 0, 0, 0, 0, 0};
            int gr = mBase + row;
            if (gr < M) {
                size_t ge = (size_t)gr * K + k0 + c * 8;
                if (AMODE == 1 || !f32) {
                    va = *(const short8*)((const ushort*)A + ge);
                } else {
                    const float* af = (const float*)A + ge;
#pragma unroll
                    for (int j = 0; j < 8; j++) va[j] = (short)f2bs(af[j]);
                }
            }
            *(short8*)&As[row * TP + c * 8] = va;

            short8 vb = {0, 0, 0, 0, 0, 0, 0, 0};
            int gn = nBase + row;
            if (gn < Nc) vb = *(const short8*)(Bt + (size_t)gn * K + k0 + c * 8);
            *(short8*)&Bs[row * TP + c * 8] = vb;
        }
        __syncthreads();

        short8 af[4], bf[4];
#pragma unroll
        for (int i = 0; i < 4; i++)
            af[i] = *(const short8*)&As[(mW + i * 16 + l15) * TP + quad * 8];
#pragma unroll
        for (int j = 0; j < 4; j++)
            bf[j] = *(const short8*)&Bs[(nW + j * 16 + l15) * TP + quad * 8];
#pragma unroll
        for (int i = 0; i < 4; i++)
#pragma unroll
            for (int j = 0; j < 4; j++)
                acc[i][j] = __builtin_amdgcn_mfma_f32_16x16x32_bf16(af[i], bf[j], acc[i][j], 0, 0, 0);
        __syncthreads();
    }

    // epilogue: C row = (lane>>4)*4 + r, col = lane&15 (HW-verified mapping)
#pragma unroll
    for (int i = 0; i < 4; i++) {
#pragma unroll
        for (int j = 0; j < 4; j++) {
            int gcn = nBase + nW + j * 16 + l15;
            if (gcn >= Nc) continue;
            float bv = ldin(bias, gcn, f32);
#pragma unroll
            for (int r = 0; r < 4; r++) {
                int grm = mBase + mW + i * 16 + quad * 4 + r;
                if (grm >= M) continue;
                float v = act_fn<ACT>(acc[i][j][r] + bv, 0.f);
                size_t oi = (size_t)grm * Nc + gcn;
                if (OMODE == 1)
                    stio(outp, 1 + oi, v, f32);
                else
                    ((ushort*)outp)[oi] = f2bs(v);
            }
        }
    }
}

// ---------------- CSR build ----------------
__global__ void count_k(const int* __restrict__ rows, int* __restrict__ counts, int nnz) {
    int i = blockIdx.x * blockDim.x + threadIdx.x;
    if (i < nnz) atomicAdd(&counts[rows[i]], 1);
}

__global__ __launch_bounds__(1024) void scan_local_k(const int* __restrict__ counts,
                                                     int* __restrict__ offs,
                                                     int* __restrict__ bsums, int n) {
    __shared__ int sm[1024];
    int t = threadIdx.x;
    int g = blockIdx.x * 1024 + t;
    int v = (g < n) ? counts[g] : 0;
    sm[t] = v;
    __syncthreads();
    for (int d = 1; d < 1024; d <<= 1) {
        int add = (t >= d) ? sm[t - d] : 0;
        __syncthreads();
        sm[t] += add;
        __syncthreads();
    }
    if (g < n) offs[g] = sm[t] - v;  // exclusive
    if (t == 1023) bsums[blockIdx.x] = sm[t];
}

__global__ void scan_bsums_k(int* bsums, int nb) {
    if (threadIdx.x == 0 && blockIdx.x == 0) {
        int acc = 0;
        for (int i = 0; i < nb; i++) {
            int v = bsums[i];
            bsums[i] = acc;
            acc += v;
        }
    }
}

__global__ void scan_add_k(int* __restrict__ offs, const int* __restrict__ bsums, int n, int nnz) {
    int g = blockIdx.x * blockDim.x + threadIdx.x;
    if (g < n) offs[g] += bsums[g >> 10];
    if (g == 0) offs[n] = nnz;
}

__global__ void fill_k(const int* __restrict__ rows, const int* __restrict__ cols,
                       const void* __restrict__ vals, const int* __restrict__ offs,
                       int* __restrict__ cursor, int* __restrict__ cols_s,
                       float* __restrict__ vals_s, const int* __restrict__ flagp, int nnz) {
    int e = blockIdx.x * blockDim.x + threadIdx.x;
    if (e < nnz) {
        int r = rows[e];
        int pos = offs[r] + atomicAdd(&cursor[r], 1);
        cols_s[pos] = cols[e];
        vals_s[pos] = ldin(vals, e, flagp[0]);
    }
}

// ---------------- SpMM (CSR, one block per dest row, bf16 in/out) ----------------
template <int ACT>
__global__ __launch_bounds__(256) void spmm_k(
    const int* __restrict__ offs, const int* __restrict__ cols_s,
    const float* __restrict__ vals_s, const int* __restrict__ perm,
    const void* __restrict__ alpha_p, const int* __restrict__ flagp,
    const ushort* __restrict__ Min, ushort* __restrict__ out, int F) {
    int row = blockIdx.x;
    int f0 = threadIdx.x;
    float alpha = (ACT == 3) ? ldin(alpha_p, 0, flagp[0]) : 0.f;
    int s = offs[row], e = offs[row + 1];
    float acc0 = 0.f, acc1 = 0.f;
    int f1 = f0 + 256;
    bool has1 = f1 < F;
    for (int i = s; i < e; i++) {
        int c = cols_s[i];
        if (perm) c = perm[c];
        float v = vals_s[i];
        const ushort* src = Min + (size_t)c * F;
        acc0 += v * ldbs(src, f0);
        if (has1) acc1 += v * ldbs(src, f1);
    }
    out[(size_t)row * F + f0] = f2bs(act_fn<ACT>(acc0, alpha));
    if (has1) out[(size_t)row * F + f1] = f2bs(act_fn<ACT>(acc1, alpha));
}

// ---------------- BatchNorm (bf16 h, in-place apply) ----------------
__global__ __launch_bounds__(256) void bn_stats_k(const ushort* __restrict__ h,
                                                  float* __restrict__ sum,
                                                  float* __restrict__ sumsq, int nrows, int rpb) {
    int c = threadIdx.x;  // blockDim == HID
    int rs = blockIdx.x * rpb;
    int re = min(rs + rpb, nrows);
    float s = 0.f, s2 = 0.f;
    int H = blockDim.x;
    for (int r = rs; r < re; r++) {
        float v = ldbs(h, (size_t)r * H + c);
        s += v;
        s2 += v * v;
    }
    atomicAdd(&sum[c], s);
    atomicAdd(&sumsq[c], s2);
}

__global__ void bn_final_k(const float* __restrict__ sum, const float* __restrict__ sumsq,
                           const void* __restrict__ gamma, const void* __restrict__ beta,
                           float* __restrict__ scale, float* __restrict__ shift,
                           const int* __restrict__ flagp, int nrows) {
    int c = threadIdx.x;
    int f32 = flagp[0];
    float mu = sum[c] / nrows;
    float var = sumsq[c] / nrows - mu * mu;
    float sc = ldin(gamma, c, f32) * rsqrtf(var + 1e-5f);
    scale[c] = sc;
    shift[c] = ldin(beta, c, f32) - mu * sc;
}

__global__ void bn_apply_k(ushort* __restrict__ h, const float* __restrict__ scale,
                           const float* __restrict__ shift) {
    int c = threadIdx.x;
    int H = blockDim.x;
    size_t i = (size_t)blockIdx.x * H + c;
    h[i] = f2bs(ldbs(h, i) * scale[c] + shift[c]);
}

// ---------------- agg scatter + MSE ----------------
__global__ void agg_k(const void* __restrict__ dout, const int* __restrict__ agg_rows,
                      const void* __restrict__ agg_vals, float* __restrict__ agg,
                      const int* __restrict__ flagp, int F) {
    int i = blockIdx.x;
    int f = threadIdx.x;
    int f32 = flagp[0];
    if (f < F) {
        int r = agg_rows[i];
        float v = ldin(agg_vals, i, f32);
        float xv = ldin(dout, (size_t)1 + (size_t)i * F + f, f32);
        atomicAdd(&agg[(size_t)r * F + f], v * xv);
    }
}

__global__ __launch_bounds__(256) void mse_k(const float* __restrict__ agg,
                                             const void* __restrict__ y,
                                             float* __restrict__ acc,
                                             const int* __restrict__ flagp, int n) {
    int f32 = flagp[0];
    float s = 0.f;
    for (int i = blockIdx.x * blockDim.x + threadIdx.x; i < n; i += gridDim.x * blockDim.x) {
        float d = agg[i] - ldin(y, i, f32);
        s += d * d;
    }
    s = blockRed(s);
    if (threadIdx.x == 0) atomicAdd(acc, s);
}

// ---------------- DGI reductions (bf16 h) ----------------
__global__ __launch_bounds__(320) void colsum_k(const ushort* __restrict__ h,
                                                float* __restrict__ accum, int nrows, int F,
                                                int rpb) {
    int f = threadIdx.x;
    if (f >= F) return;
    int rs = blockIdx.x * rpb;
    int re = min(rs + rpb, nrows);
    float s = 0.f;
    for (int r = rs; r < re; r++) s += ldbs(h, (size_t)r * F + f);
    atomicAdd(&accum[f], s);
}

__global__ __launch_bounds__(320) void cfinal_k(const float* __restrict__ accum,
                                                float* __restrict__ c, float* __restrict__ cnorm,
                                                int N, int F) {
    int f = threadIdx.x;
    float v = 0.f;
    if (f < F) {
        v = accum[f] / N;
        c[f] = v;
    }
    float s2 = blockRed(v * v);
    if (threadIdx.x == 0) cnorm[0] = sqrtf(s2);
}

// MODE 0: sum += cos ; MODE 1: sum += max(cos,0)
template <int MODE>
__global__ __launch_bounds__(256) void cos_k(const ushort* __restrict__ h,
                                             const float* __restrict__ c,
                                             const float* __restrict__ cnorm,
                                             float* __restrict__ acc, int N, int F) {
    int gw = (blockIdx.x * blockDim.x + threadIdx.x) >> 6;
    int lane = threadIdx.x & 63;
    int nw = (gridDim.x * blockDim.x) >> 6;
    float cn = cnorm[0];
    float s = 0.f;
    for (int row = gw; row < N; row += nw) {
        float dot = 0.f, nsq = 0.f;
        for (int f = lane; f < F; f += 64) {
            float v = ldbs(h, (size_t)row * F + f);
            dot += v * c[f];
            nsq += v * v;
        }
#pragma unroll
        for (int o = 32; o > 0; o >>= 1) {
            dot += __shfl_down(dot, o);
            nsq += __shfl_down(nsq, o);
        }
        if (lane == 0) {
            float cosv = dot / fmaxf(sqrtf(nsq) * cn, 1e-8f);
            s += (MODE == 1) ? fmaxf(cosv, 0.f) : cosv;
        }
    }
    s = blockRed(s);
    if (threadIdx.x == 0) atomicAdd(acc, s);
}

__global__ void final_k(const float* __restrict__ lacc, void* __restrict__ dout,
                        const int* __restrict__ flagp, int SOUT, int N) {
    if (threadIdx.x == 0 && blockIdx.x == 0) {
        float loss = lacc[0] / SOUT + (1.f - lacc[1] / N) + lacc[2] / N;
        stio(dout, 0, loss, flagp[0]);
    }
}

// ---------------- launch ----------------
extern "C" void kernel_launch(void* const* d_in, const int* in_sizes, int n_in,
                              void* d_out, int out_size, void* d_ws, size_t ws_size,
                              hipStream_t stream) {
    const void* x = d_in[0];
    const void* y = d_in[1];
    const int* adj_rows = (const int*)d_in[2];
    const int* adj_cols = (const int*)d_in[3];
    const void* adj_vals = d_in[4];
    const int* agg_rows = (const int*)d_in[5];
    const void* agg_vals = d_in[6];
    const int* perm = (const int*)d_in[7];
    const void* mlp_W = d_in[8];
    const void* mlp_b = d_in[9];
    const void* bn_gamma = d_in[10];
    const void* bn_beta = d_in[11];
    const void* hg_W1 = d_in[12];
    const void* hg_b1 = d_in[13];
    const void* hg_W2 = d_in[14];
    const void* hg_b2 = d_in[15];
    const void* hg_prelu = d_in[16];
    const void* pred_W = d_in[17];
    const void* pred_b = d_in[18];
    const void* dgi_W = d_in[19];
    const void* dgi_b = d_in[20];
    const void* dgi_prelu = d_in[21];

    const int N = in_sizes[5];         // 50000
    const int NNZ = in_sizes[2];       // 800000
    const int F_IN = in_sizes[0] / N;  // 1024
    const int HID = in_sizes[9];       // 256
    const int OUT = in_sizes[18];      // 280
    const int S = in_sizes[1] / OUT;   // 5000

    // workspace carve-up
    char* w = (char*)d_ws;
    size_t off = 0;
    auto alloc = [&](size_t b) -> char* {
        char* p = w + off;
        off += (b + 255) & ~(size_t)255;
        return p;
    };
    ushort* h0_bf = (ushort*)alloc((size_t)N * HID * 2);  // h0 (bf16, BN applied in place)
    ushort* zA_bf = (ushort*)alloc((size_t)N * OUT * 2);  // GEMM outs
    ushort* zB_bf = (ushort*)alloc((size_t)N * OUT * 2);  // spmm outs
    ushort* mlpWt = (ushort*)alloc((size_t)HID * F_IN * 2);
    ushort* hgW1t = (ushort*)alloc((size_t)HID * HID * 2);
    ushort* hgW2t = (ushort*)alloc((size_t)HID * HID * 2);
    ushort* predWt = (ushort*)alloc((size_t)OUT * HID * 2);
    ushort* dgiWt = (ushort*)alloc((size_t)OUT * HID * 2);
    float* aggb = (float*)alloc((size_t)S * OUT * 4);
    int* counts = (int*)alloc((size_t)N * 4);
    int* cursor = (int*)alloc((size_t)N * 4);
    int* offs = (int*)alloc((size_t)(N + 1) * 4);
    int nbscan = (N + 1023) / 1024;
    int* bsums = (int*)alloc((size_t)nbscan * 4);
    int* cols_s = (int*)alloc((size_t)NNZ * 4);
    float* vals_s = (float*)alloc((size_t)NNZ * 4);
    float* bn_sum = (float*)alloc((size_t)HID * 4);
    float* bn_sumsq = (float*)alloc((size_t)HID * 4);
    float* bn_scale = (float*)alloc((size_t)HID * 4);
    float* bn_shift = (float*)alloc((size_t)HID * 4);
    float* c_acc = (float*)alloc((size_t)OUT * 4);
    float* c_vec = (float*)alloc((size_t)OUT * 4);
    float* cnorm = (float*)alloc(4);
    float* lacc = (float*)alloc(16);
    int* dflag = (int*)alloc(16);

    // zero what accumulates
    hipMemsetAsync(counts, 0, (size_t)N * 4, stream);
    hipMemsetAsync(cursor, 0, (size_t)N * 4, stream);
    hipMemsetAsync(bn_sum, 0, (size_t)HID * 4, stream);
    hipMemsetAsync(bn_sumsq, 0, (size_t)HID * 4, stream);
    hipMemsetAsync(c_acc, 0, (size_t)OUT * 4, stream);
    hipMemsetAsync(lacc, 0, 16, stream);
    hipMemsetAsync(aggb, 0, (size_t)S * OUT * 4, stream);

    // dtype probe (dflag[0]: 1 = float32 inputs, 0 = bf16 inputs)
    probe_k<<<1, 256, 0, stream>>>(x, dflag);

    // weight transpose+convert to bf16 [N][K]
    cvt_wt_k<<<(F_IN * HID + 255) / 256, 256, 0, stream>>>(mlp_W, mlpWt, dflag, F_IN, HID);
    cvt_wt_k<<<(HID * HID + 255) / 256, 256, 0, stream>>>(hg_W1, hgW1t, dflag, HID, HID);
    cvt_wt_k<<<(HID * HID + 255) / 256, 256, 0, stream>>>(hg_W2, hgW2t, dflag, HID, HID);
    cvt_wt_k<<<(HID * OUT + 255) / 256, 256, 0, stream>>>(pred_W, predWt, dflag, HID, OUT);
    cvt_wt_k<<<(HID * OUT + 255) / 256, 256, 0, stream>>>(dgi_W, dgiWt, dflag, HID, OUT);

    // CSR build (reused by all 4 spmms)
    count_k<<<(NNZ + 255) / 256, 256, 0, stream>>>(adj_rows, counts, NNZ);
    scan_local_k<<<nbscan, 1024, 0, stream>>>(counts, offs, bsums, N);
    scan_bsums_k<<<1, 64, 0, stream>>>(bsums, nbscan);
    scan_add_k<<<(N + 255) / 256, 256, 0, stream>>>(offs, bsums, N, NNZ);
    fill_k<<<(NNZ + 255) / 256, 256, 0, stream>>>(adj_rows, adj_cols, adj_vals, offs, cursor,
                                                  cols_s, vals_s, dflag, NNZ);

    const int MT = (N + 127) / 128;
    // h0 = leaky(x @ mlp_W + b, 0.1)  [MFMA]
    mgemm_k<0, 1, 0><<<dim3(MT, (HID + 127) / 128), 256, 0, stream>>>(x, mlpWt, mlp_b, h0_bf,
                                                                      dflag, N, F_IN, HID);
    // BatchNorm (training-mode batch stats), in-place on h0_bf
    bn_stats_k<<<(N + 127) / 128, HID, 0, stream>>>(h0_bf, bn_sum, bn_sumsq, N, 128);
    bn_final_k<<<1, HID, 0, stream>>>(bn_sum, bn_sumsq, bn_gamma, bn_beta, bn_scale, bn_shift,
                                      dflag, N);
    bn_apply_k<<<N, HID, 0, stream>>>(h0_bf, bn_scale, bn_shift);

    // HGNN layer 1
    mgemm_k<1, 0, 0><<<dim3(MT, (HID + 127) / 128), 256, 0, stream>>>(h0_bf, hgW1t, hg_b1, zA_bf,
                                                                      dflag, N, HID, HID);
    spmm_k<3><<<N, 256, 0, stream>>>(offs, cols_s, vals_s, nullptr, hg_prelu, dflag, zA_bf, zB_bf,
                                     HID);
    // HGNN layer 2
    mgemm_k<1, 0, 0><<<dim3(MT, (HID + 127) / 128), 256, 0, stream>>>(zB_bf, hgW2t, hg_b2, zA_bf,
                                                                      dflag, N, HID, HID);
    spmm_k<2><<<N, 256, 0, stream>>>(offs, cols_s, vals_s, nullptr, nullptr, dflag, zA_bf, zB_bf,
                                     HID);

    // x_prime = leaky(h @ pred_W + b, 0.01) -> d_out elements [1 ...]
    mgemm_k<1, 2, 1><<<dim3(MT, (OUT + 127) / 128), 256, 0, stream>>>(zB_bf, predWt, pred_b, d_out,
                                                                      dflag, N, HID, OUT);
    // agg = segment_sum(agg_vals * x_prime); mse
    agg_k<<<N, 320, 0, stream>>>(d_out, agg_rows, agg_vals, aggb, dflag, OUT);
    mse_k<<<256, 256, 0, stream>>>(aggb, y, &lacc[0], dflag, S * OUT);

    // DGI: z = h0 @ dgi_W + b ; h1 = prelu(spmm(z)) ; h2 = prelu(spmm(z via perm[col]))
    mgemm_k<1, 0, 0><<<dim3(MT, (OUT + 127) / 128), 256, 0, stream>>>(h0_bf, dgiWt, dgi_b, zA_bf,
                                                                      dflag, N, HID, OUT);
    spmm_k<3><<<N, 256, 0, stream>>>(offs, cols_s, vals_s, nullptr, dgi_prelu, dflag, zA_bf, zB_bf,
                                     OUT);
    colsum_k<<<(N + 127) / 128, 320, 0, stream>>>(zB_bf, c_acc, N, OUT, 128);
    cfinal_k<<<1, 320, 0, stream>>>(c_acc, c_vec, cnorm, N, OUT);
    cos_k<0><<<256, 256, 0, stream>>>(zB_bf, c_vec, cnorm, &lacc[1], N, OUT);
    spmm_k<3><<<N, 256, 0, stream>>>(offs, cols_s, vals_s, perm, dgi_prelu, dflag, zA_bf, zB_bf,
                                     OUT);
    cos_k<1><<<256, 256, 0, stream>>>(zB_bf, c_vec, cnorm, &lacc[2], N, OUT);

    final_k<<<1, 64, 0, stream>>>(lacc, d_out, dflag, S * OUT, N);
}

// Round 4
// 1365.377 us; speedup vs baseline: 2.0681x; 1.2963x over previous
//
#include <hip/hip_runtime.h>
#include <hip/hip_bf16.h>

#define DEVI __device__ __forceinline__

typedef __attribute__((ext_vector_type(8))) short short8;
typedef __attribute__((ext_vector_type(4))) float float4v;

DEVI float bf2f(__hip_bfloat16 v) { return __bfloat162float(v); }
DEVI float ldbs(const ushort* p, size_t i) { return bf2f(((const __hip_bfloat16*)p)[i]); }
DEVI ushort f2bs(float v) {
    __hip_bfloat16 h = __float2bfloat16(v);
    return *(ushort*)&h;
}
DEVI float bfs2f(short s) {
    ushort u = (ushort)s;
    return bf2f(*(__hip_bfloat16*)&u);
}

// flag-dependent element load/store: isf32 selects float32 vs bf16 view
DEVI float ldin(const void* p, size_t i, int isf32) {
    return isf32 ? ((const float*)p)[i] : bf2f(((const __hip_bfloat16*)p)[i]);
}
DEVI void stio(void* p, size_t i, float v, int isf32) {
    if (isf32) ((float*)p)[i] = v;
    else ((ushort*)p)[i] = f2bs(v);
}

// ACT: 0 none, 1 leaky(0.1), 2 leaky(0.01), 3 prelu(alpha)
template <int ACT>
DEVI float act_fn(float v, float alpha) {
    if (ACT == 1) return v >= 0.f ? v : 0.1f * v;
    if (ACT == 2) return v >= 0.f ? v : 0.01f * v;
    if (ACT == 3) return v >= 0.f ? v : alpha * v;
    return v;
}

DEVI float waveRed(float v) {
#pragma unroll
    for (int o = 32; o > 0; o >>= 1) v += __shfl_down(v, o);
    return v;
}

DEVI float blockRed(float v) {
    __shared__ float sm[16];
    int lane = threadIdx.x & 63, w = threadIdx.x >> 6;
    v = waveRed(v);
    if (lane == 0) sm[w] = v;
    __syncthreads();
    if (w == 0) {
        int nw = (blockDim.x + 63) >> 6;
        v = (lane < nw) ? sm[lane] : 0.f;
        v = waveRed(v);
    }
    return v;  // valid on thread 0
}

// ---------------- dtype probe ----------------
__global__ void probe_k(const void* __restrict__ x, int* __restrict__ flag) {
    __shared__ int sfails;
    int t = threadIdx.x;
    if (t == 0) sfails = 0;
    __syncthreads();
    const __hip_bfloat16* xb = (const __hip_bfloat16*)x;
    int my = 0;
    for (int i = t; i < 4096; i += 256) {
        float v = bf2f(xb[i]);
        float a = fabsf(v);
        if (!(a <= 64.f) || (v != 0.f && a < 1e-6f)) my++;
    }
    atomicAdd(&sfails, my);
    __syncthreads();
    if (t == 0) flag[0] = (sfails > 409) ? 1 : 0;  // >10% fail => inputs are float32
}

// ---------------- fused weight transpose+convert (5 weights in one launch) ----
struct Cvt5 {
    const void* src[5];
    ushort* dst[5];
    int K[5];
    int N[5];
};
__global__ void cvt_all_k(Cvt5 d, const int* __restrict__ flagp) {
    int f32 = flagp[0];
    int seg = blockIdx.y;
    int idx = blockIdx.x * blockDim.x + threadIdx.x;
    int K = d.K[seg], Nc = d.N[seg];
    int total = K * Nc;
    if (idx < total) {
        int k = idx / Nc, n = idx % Nc;
        d.dst[seg][(size_t)n * K + k] = f2bs(ldin(d.src[seg], idx, f32));
    }
}

// ---------------- MFMA bf16 GEMM ----------------
// C[M][Nc] = act(A[M][K] @ Bt[Nc][K]^T + bias)
// 128x128 tile, 256 threads (4 waves 2x2), 16x16x32 MFMA, BK=32, pitch 40 shorts.
// AMODE: 0 = A is flag-typed model input, 1 = A is bf16 workspace
// OMODE: 0 = out bf16 workspace, 1 = out is d_out (flag-typed, +1 elem) AND outp2 bf16 ws
#define TP 40
template <int AMODE, int ACT, int OMODE>
__global__ __launch_bounds__(256) void mgemm_k(
    const void* __restrict__ A, const ushort* __restrict__ Bt,
    const void* __restrict__ bias, void* __restrict__ outp, ushort* __restrict__ outp2,
    const int* __restrict__ flagp, int M, int K, int Nc) {
    __shared__ short As[128 * TP];
    __shared__ short Bs[128 * TP];
    const int f32 = flagp[0];
    const int tid = threadIdx.x;
    const int lane = tid & 63;
    const int l15 = lane & 15;
    const int quad = lane >> 4;
    const int wid = tid >> 6;
    const int mW = (wid >> 1) * 64;
    const int nW = (wid & 1) * 64;
    const int mBase = blockIdx.x * 128;
    const int nBase = blockIdx.y * 128;

    float4v acc[4][4];
#pragma unroll
    for (int i = 0; i < 4; i++)
#pragma unroll
        for (int j = 0; j < 4; j++) acc[i][j] = (float4v){0.f, 0.f, 0.f, 0.f};

    for (int k0 = 0; k0 < K; k0 += 32) {
#pragma unroll
        for (int i = 0; i < 2; i++) {
            int chunk = i * 256 + tid;
            int row = chunk >> 2;
            int c = chunk & 3;
            short8 va = {0, 0, 0, 0, 0, 0, 0, 0};
            int gr = mBase + row;
            if (gr < M) {
                size_t ge = (size_t)gr * K + k0 + c * 8;
                if (AMODE == 1 || !f32) {
                    va = *(const short8*)((const ushort*)A + ge);
                } else {
                    const float* af = (const float*)A + ge;
#pragma unroll
                    for (int j = 0; j < 8; j++) va[j] = (short)f2bs(af[j]);
                }
            }
            *(short8*)&As[row * TP + c * 8] = va;

            short8 vb = {0, 0, 0, 0, 0, 0, 0, 0};
            int gn = nBase + row;
            if (gn < Nc) vb = *(const short8*)(Bt + (size_t)gn * K + k0 + c * 8);
            *(short8*)&Bs[row * TP + c * 8] = vb;
        }
        __syncthreads();

        short8 af[4], bf[4];
#pragma unroll
        for (int i = 0; i < 4; i++)
            af[i] = *(const short8*)&As[(mW + i * 16 + l15) * TP + quad * 8];
#pragma unroll
        for (int j = 0; j < 4; j++)
            bf[j] = *(const short8*)&Bs[(nW + j * 16 + l15) * TP + quad * 8];
#pragma unroll
        for (int i = 0; i < 4; i++)
#pragma unroll
            for (int j = 0; j < 4; j++)
                acc[i][j] =
                    __builtin_amdgcn_mfma_f32_16x16x32_bf16(af[i], bf[j], acc[i][j], 0, 0, 0);
        __syncthreads();
    }

#pragma unroll
    for (int i = 0; i < 4; i++) {
#pragma unroll
        for (int j = 0; j < 4; j++) {
            int gcn = nBase + nW + j * 16 + l15;
            if (gcn >= Nc) continue;
            float bv = ldin(bias, gcn, f32);
#pragma unroll
            for (int r = 0; r < 4; r++) {
                int grm = mBase + mW + i * 16 + quad * 4 + r;
                if (grm >= M) continue;
                float v = act_fn<ACT>(acc[i][j][r] + bv, 0.f);
                size_t oi = (size_t)grm * Nc + gcn;
                if (OMODE == 1) {
                    stio(outp, 1 + oi, v, f32);
                    outp2[oi] = f2bs(v);
                } else {
                    ((ushort*)outp)[oi] = f2bs(v);
                }
            }
        }
    }
}

// ---------------- CSR build (generic: used for adjacency and agg segments) ---
__global__ void count_k(const int* __restrict__ rows, int* __restrict__ counts, int nnz) {
    int i = blockIdx.x * blockDim.x + threadIdx.x;
    if (i < nnz) atomicAdd(&counts[rows[i]], 1);
}

__global__ __launch_bounds__(1024) void scan_local_k(const int* __restrict__ counts,
                                                     int* __restrict__ offs,
                                                     int* __restrict__ bsums, int n) {
    __shared__ int sm[1024];
    int t = threadIdx.x;
    int g = blockIdx.x * 1024 + t;
    int v = (g < n) ? counts[g] : 0;
    sm[t] = v;
    __syncthreads();
    for (int d = 1; d < 1024; d <<= 1) {
        int add = (t >= d) ? sm[t - d] : 0;
        __syncthreads();
        sm[t] += add;
        __syncthreads();
    }
    if (g < n) offs[g] = sm[t] - v;  // exclusive
    if (t == 1023) bsums[blockIdx.x] = sm[t];
}

__global__ void scan_bsums_k(int* bsums, int nb) {
    if (threadIdx.x == 0 && blockIdx.x == 0) {
        int acc = 0;
        for (int i = 0; i < nb; i++) {
            int v = bsums[i];
            bsums[i] = acc;
            acc += v;
        }
    }
}

__global__ void scan_add_k(int* __restrict__ offs, const int* __restrict__ bsums, int n, int nnz) {
    int g = blockIdx.x * blockDim.x + threadIdx.x;
    if (g < n) offs[g] += bsums[g >> 10];
    if (g == 0) offs[n] = nnz;
}

// adjacency fill: also pre-applies perm to build colsp
__global__ void fill_k(const int* __restrict__ rows, const int* __restrict__ cols,
                       const void* __restrict__ vals, const int* __restrict__ perm,
                       const int* __restrict__ offs, int* __restrict__ cursor,
                       int* __restrict__ cols_s, int* __restrict__ colsp_s,
                       float* __restrict__ vals_s, const int* __restrict__ flagp, int nnz) {
    int e = blockIdx.x * blockDim.x + threadIdx.x;
    if (e < nnz) {
        int r = rows[e];
        int pos = offs[r] + atomicAdd(&cursor[r], 1);
        int c = cols[e];
        cols_s[pos] = c;
        colsp_s[pos] = perm[c];
        vals_s[pos] = ldin(vals, e, flagp[0]);
    }
}

// agg segment fill (source index = element position)
__global__ void fill_s_k(const int* __restrict__ rows, const void* __restrict__ vals,
                         const int* __restrict__ offs, int* __restrict__ cursor,
                         int* __restrict__ idx_s, float* __restrict__ val_s,
                         const int* __restrict__ flagp, int n) {
    int e = blockIdx.x * blockDim.x + threadIdx.x;
    if (e < n) {
        int r = rows[e];
        int pos = offs[r] + atomicAdd(&cursor[r], 1);
        idx_s[pos] = e;
        val_s[pos] = ldin(vals, e, flagp[0]);
    }
}

// ---------------- vectorized SpMM: one wave per dest row, 16B gathers --------
// lanes: half = lane>>5 processes edges s+half, s+half+2, ...
//        l5 = lane&31 owns bf16 chunk l5 (8 feats) and chunk l5+32 if F > 256
// DUAL: also gathers via colsp (perm) into out2 (DGI h1+h2 in one pass)
template <int ACT, bool DUAL>
__global__ __launch_bounds__(256) void spmmv_k(
    const int* __restrict__ offs, const int* __restrict__ cols_s,
    const int* __restrict__ colsp_s, const float* __restrict__ vals_s,
    const void* __restrict__ alpha_p, const int* __restrict__ flagp,
    const ushort* __restrict__ Min, ushort* __restrict__ out1, ushort* __restrict__ out2,
    int Nrow, int F) {
    int row = blockIdx.x * 4 + (threadIdx.x >> 6);
    if (row >= Nrow) return;
    int lane = threadIdx.x & 63;
    int half = lane >> 5, l5 = lane & 31;
    int FC = F >> 3;
    bool has1 = (l5 + 32) < FC;
    float alpha = (ACT == 3) ? ldin(alpha_p, 0, flagp[0]) : 0.f;
    int s = offs[row], e = offs[row + 1];
    float a0[8] = {}, a1[8] = {}, b0[8] = {}, b1[8] = {};
#pragma unroll 2
    for (int i = s + half; i < e; i += 2) {
        float v = vals_s[i];
        int c = cols_s[i];
        const ushort* src = Min + (size_t)c * F;
        short8 h = *(const short8*)(src + l5 * 8);
#pragma unroll
        for (int j = 0; j < 8; j++) a0[j] += v * bfs2f(h[j]);
        if (has1) {
            short8 h2 = *(const short8*)(src + (l5 + 32) * 8);
#pragma unroll
            for (int j = 0; j < 8; j++) a1[j] += v * bfs2f(h2[j]);
        }
        if (DUAL) {
            int cp = colsp_s[i];
            const ushort* srcp = Min + (size_t)cp * F;
            short8 g = *(const short8*)(srcp + l5 * 8);
#pragma unroll
            for (int j = 0; j < 8; j++) b0[j] += v * bfs2f(g[j]);
            if (has1) {
                short8 g2 = *(const short8*)(srcp + (l5 + 32) * 8);
#pragma unroll
                for (int j = 0; j < 8; j++) b1[j] += v * bfs2f(g2[j]);
            }
        }
    }
#pragma unroll
    for (int j = 0; j < 8; j++) {
        a0[j] += __shfl_xor(a0[j], 32);
        if (has1) a1[j] += __shfl_xor(a1[j], 32);
        if (DUAL) {
            b0[j] += __shfl_xor(b0[j], 32);
            if (has1) b1[j] += __shfl_xor(b1[j], 32);
        }
    }
    if (half == 0) {
        short8 o;
        size_t base = (size_t)row * F;
#pragma unroll
        for (int j = 0; j < 8; j++) o[j] = (short)f2bs(act_fn<ACT>(a0[j], alpha));
        *(short8*)(out1 + base + l5 * 8) = o;
        if (has1) {
#pragma unroll
            for (int j = 0; j < 8; j++) o[j] = (short)f2bs(act_fn<ACT>(a1[j], alpha));
            *(short8*)(out1 + base + (l5 + 32) * 8) = o;
        }
        if (DUAL) {
#pragma unroll
            for (int j = 0; j < 8; j++) o[j] = (short)f2bs(act_fn<ACT>(b0[j], alpha));
            *(short8*)(out2 + base + l5 * 8) = o;
            if (has1) {
#pragma unroll
                for (int j = 0; j < 8; j++) o[j] = (short)f2bs(act_fn<ACT>(b1[j], alpha));
                *(short8*)(out2 + base + (l5 + 32) * 8) = o;
            }
        }
    }
}

// ---------------- fused agg segment-sum + MSE (gather, no atomics on agg) ----
__global__ __launch_bounds__(256) void aggmse_k(
    const int* __restrict__ soffs, const int* __restrict__ sidx, const float* __restrict__ sval,
    const ushort* __restrict__ xp, const void* __restrict__ y, const int* __restrict__ flagp,
    float* __restrict__ lacc, int S, int F) {
    int srow = blockIdx.x * 4 + (threadIdx.x >> 6);
    int lane = threadIdx.x & 63;
    int half = lane >> 5, l5 = lane & 31;
    int FC = F >> 3;
    bool has1 = (l5 + 32) < FC;
    float a0[8] = {}, a1[8] = {};
    if (srow < S) {
        int s = soffs[srow], e = soffs[srow + 1];
        for (int i = s + half; i < e; i += 2) {
            float v = sval[i];
            int n = sidx[i];
            const ushort* src = xp + (size_t)n * F;
            short8 h = *(const short8*)(src + l5 * 8);
#pragma unroll
            for (int j = 0; j < 8; j++) a0[j] += v * bfs2f(h[j]);
            if (has1) {
                short8 h2 = *(const short8*)(src + (l5 + 32) * 8);
#pragma unroll
                for (int j = 0; j < 8; j++) a1[j] += v * bfs2f(h2[j]);
            }
        }
    }
#pragma unroll
    for (int j = 0; j < 8; j++) {
        a0[j] += __shfl_xor(a0[j], 32);
        if (has1) a1[j] += __shfl_xor(a1[j], 32);
    }
    float ss = 0.f;
    if (srow < S && half == 0) {
        int f32 = flagp[0];
        size_t base = (size_t)srow * F;
#pragma unroll
        for (int j = 0; j < 8; j++) {
            float d = a0[j] - ldin(y, base + l5 * 8 + j, f32);
            ss += d * d;
        }
        if (has1) {
#pragma unroll
            for (int j = 0; j < 8; j++) {
                float d = a1[j] - ldin(y, base + (l5 + 32) * 8 + j, f32);
                ss += d * d;
            }
        }
    }
    ss = blockRed(ss);
    if (threadIdx.x == 0) atomicAdd(&lacc[0], ss);
}

// ---------------- BatchNorm (bf16 h, in-place apply) ----------------
__global__ __launch_bounds__(256) void bn_stats_k(const ushort* __restrict__ h,
                                                  float* __restrict__ sum,
                                                  float* __restrict__ sumsq, int nrows, int rpb) {
    int c = threadIdx.x;
    int rs = blockIdx.x * rpb;
    int re = min(rs + rpb, nrows);
    float s = 0.f, s2 = 0.f;
    int H = blockDim.x;
    for (int r = rs; r < re; r++) {
        float v = ldbs(h, (size_t)r * H + c);
        s += v;
        s2 += v * v;
    }
    atomicAdd(&sum[c], s);
    atomicAdd(&sumsq[c], s2);
}

__global__ void bn_final_k(const float* __restrict__ sum, const float* __restrict__ sumsq,
                           const void* __restrict__ gamma, const void* __restrict__ beta,
                           float* __restrict__ scale, float* __restrict__ shift,
                           const int* __restrict__ flagp, int nrows) {
    int c = threadIdx.x;
    int f32 = flagp[0];
    float mu = sum[c] / nrows;
    float var = sumsq[c] / nrows - mu * mu;
    float sc = ldin(gamma, c, f32) * rsqrtf(var + 1e-5f);
    scale[c] = sc;
    shift[c] = ldin(beta, c, f32) - mu * sc;
}

__global__ void bn_apply_k(ushort* __restrict__ h, const float* __restrict__ scale,
                           const float* __restrict__ shift) {
    int c = threadIdx.x;
    int H = blockDim.x;
    size_t i = (size_t)blockIdx.x * H + c;
    h[i] = f2bs(ldbs(h, i) * scale[c] + shift[c]);
}

// ---------------- DGI reductions (bf16 h) ----------------
__global__ __launch_bounds__(320) void colsum_k(const ushort* __restrict__ h,
                                                float* __restrict__ accum, int nrows, int F,
                                                int rpb) {
    int f = threadIdx.x;
    if (f >= F) return;
    int rs = blockIdx.x * rpb;
    int re = min(rs + rpb, nrows);
    float s = 0.f;
    for (int r = rs; r < re; r++) s += ldbs(h, (size_t)r * F + f);
    atomicAdd(&accum[f], s);
}

__global__ __launch_bounds__(320) void cfinal_k(const float* __restrict__ accum,
                                                float* __restrict__ c, float* __restrict__ cnorm,
                                                int N, int F) {
    int f = threadIdx.x;
    float v = 0.f;
    if (f < F) {
        v = accum[f] / N;
        c[f] = v;
    }
    float s2 = blockRed(v * v);
    if (threadIdx.x == 0) cnorm[0] = sqrtf(s2);
}

// MODE 0: sum += cos ; MODE 1: sum += max(cos,0)
template <int MODE>
__global__ __launch_bounds__(256) void cos_k(const ushort* __restrict__ h,
                                             const float* __restrict__ c,
                                             const float* __restrict__ cnorm,
                                             float* __restrict__ acc, int N, int F) {
    int gw = (blockIdx.x * blockDim.x + threadIdx.x) >> 6;
    int lane = threadIdx.x & 63;
    int nw = (gridDim.x * blockDim.x) >> 6;
    float cn = cnorm[0];
    float s = 0.f;
    for (int row = gw; row < N; row += nw) {
        float dot = 0.f, nsq = 0.f;
        for (int f = lane; f < F; f += 64) {
            float v = ldbs(h, (size_t)row * F + f);
            dot += v * c[f];
            nsq += v * v;
        }
#pragma unroll
        for (int o = 32; o > 0; o >>= 1) {
            dot += __shfl_down(dot, o);
            nsq += __shfl_down(nsq, o);
        }
        if (lane == 0) {
            float cosv = dot / fmaxf(sqrtf(nsq) * cn, 1e-8f);
            s += (MODE == 1) ? fmaxf(cosv, 0.f) : cosv;
        }
    }
    s = blockRed(s);
    if (threadIdx.x == 0) atomicAdd(acc, s);
}

__global__ void final_k(const float* __restrict__ lacc, void* __restrict__ dout,
                        const int* __restrict__ flagp, int SOUT, int N) {
    if (threadIdx.x == 0 && blockIdx.x == 0) {
        float loss = lacc[0] / SOUT + (1.f - lacc[1] / N) + lacc[2] / N;
        stio(dout, 0, loss, flagp[0]);
    }
}

// ---------------- launch ----------------
extern "C" void kernel_launch(void* const* d_in, const int* in_sizes, int n_in,
                              void* d_out, int out_size, void* d_ws, size_t ws_size,
                              hipStream_t stream) {
    const void* x = d_in[0];
    const void* y = d_in[1];
    const int* adj_rows = (const int*)d_in[2];
    const int* adj_cols = (const int*)d_in[3];
    const void* adj_vals = d_in[4];
    const int* agg_rows = (const int*)d_in[5];
    const void* agg_vals = d_in[6];
    const int* perm = (const int*)d_in[7];
    const void* mlp_W = d_in[8];
    const void* mlp_b = d_in[9];
    const void* bn_gamma = d_in[10];
    const void* bn_beta = d_in[11];
    const void* hg_W1 = d_in[12];
    const void* hg_b1 = d_in[13];
    const void* hg_W2 = d_in[14];
    const void* hg_b2 = d_in[15];
    const void* hg_prelu = d_in[16];
    const void* pred_W = d_in[17];
    const void* pred_b = d_in[18];
    const void* dgi_W = d_in[19];
    const void* dgi_b = d_in[20];
    const void* dgi_prelu = d_in[21];

    const int N = in_sizes[5];         // 50000
    const int NNZ = in_sizes[2];       // 800000
    const int F_IN = in_sizes[0] / N;  // 1024
    const int HID = in_sizes[9];       // 256
    const int OUT = in_sizes[18];      // 280
    const int S = in_sizes[1] / OUT;   // 5000

    // workspace carve-up
    char* w = (char*)d_ws;
    size_t off = 0;
    auto alloc = [&](size_t b) -> char* {
        char* p = w + off;
        off += (b + 255) & ~(size_t)255;
        return p;
    };
    ushort* h0_bf = (ushort*)alloc((size_t)N * HID * 2);   // h0 (BN in place)
    ushort* zA_bf = (ushort*)alloc((size_t)N * OUT * 2);   // GEMM outs
    ushort* zB_bf = (ushort*)alloc((size_t)N * OUT * 2);   // spmm outs / h1
    ushort* h2_bf = (ushort*)alloc((size_t)N * OUT * 2);   // DGI h2
    ushort* xp_ws = (ushort*)alloc((size_t)N * OUT * 2);   // aligned x_prime copy
    ushort* mlpWt = (ushort*)alloc((size_t)HID * F_IN * 2);
    ushort* hgW1t = (ushort*)alloc((size_t)HID * HID * 2);
    ushort* hgW2t = (ushort*)alloc((size_t)HID * HID * 2);
    ushort* predWt = (ushort*)alloc((size_t)OUT * HID * 2);
    ushort* dgiWt = (ushort*)alloc((size_t)OUT * HID * 2);
    int* offs = (int*)alloc((size_t)(N + 1) * 4);
    int nbscan = (N + 1023) / 1024;
    int* bsums = (int*)alloc((size_t)nbscan * 4);
    int* cols_s = (int*)alloc((size_t)NNZ * 4);
    int* colsp_s = (int*)alloc((size_t)NNZ * 4);
    float* vals_s = (float*)alloc((size_t)NNZ * 4);
    int* soffs = (int*)alloc((size_t)(S + 1) * 4);
    int nbscan_s = (S + 1023) / 1024;
    int* sbsums = (int*)alloc((size_t)nbscan_s * 4);
    int* sidx = (int*)alloc((size_t)N * 4);
    float* sval = (float*)alloc((size_t)N * 4);
    float* bn_scale = (float*)alloc((size_t)HID * 4);
    float* bn_shift = (float*)alloc((size_t)HID * 4);
    float* c_vec = (float*)alloc((size_t)OUT * 4);
    float* cnorm = (float*)alloc(4);
    int* dflag = (int*)alloc(16);
    // ---- contiguous zero region (single memset) ----
    char* zero_base = w + off;
    int* counts = (int*)alloc((size_t)N * 4);
    int* cursor = (int*)alloc((size_t)N * 4);
    int* scnt = (int*)alloc((size_t)S * 4);
    int* scursor = (int*)alloc((size_t)S * 4);
    float* bn_sum = (float*)alloc((size_t)HID * 4);
    float* bn_sumsq = (float*)alloc((size_t)HID * 4);
    float* c_acc = (float*)alloc((size_t)OUT * 4);
    float* lacc = (float*)alloc(16);
    size_t zero_bytes = (w + off) - zero_base;
    hipMemsetAsync(zero_base, 0, zero_bytes, stream);

    // dtype probe (dflag[0]: 1 = float32 inputs, 0 = bf16 inputs)
    probe_k<<<1, 256, 0, stream>>>(x, dflag);

    // fused weight transpose+convert
    Cvt5 cv;
    cv.src[0] = mlp_W;  cv.dst[0] = mlpWt;  cv.K[0] = F_IN; cv.N[0] = HID;
    cv.src[1] = hg_W1;  cv.dst[1] = hgW1t;  cv.K[1] = HID;  cv.N[1] = HID;
    cv.src[2] = hg_W2;  cv.dst[2] = hgW2t;  cv.K[2] = HID;  cv.N[2] = HID;
    cv.src[3] = pred_W; cv.dst[3] = predWt; cv.K[3] = HID;  cv.N[3] = OUT;
    cv.src[4] = dgi_W;  cv.dst[4] = dgiWt;  cv.K[4] = HID;  cv.N[4] = OUT;
    cvt_all_k<<<dim3((F_IN * HID + 255) / 256, 5), 256, 0, stream>>>(cv, dflag);

    // adjacency CSR
    count_k<<<(NNZ + 255) / 256, 256, 0, stream>>>(adj_rows, counts, NNZ);
    scan_local_k<<<nbscan, 1024, 0, stream>>>(counts, offs, bsums, N);
    scan_bsums_k<<<1, 64, 0, stream>>>(bsums, nbscan);
    scan_add_k<<<(N + 255) / 256, 256, 0, stream>>>(offs, bsums, N, NNZ);
    fill_k<<<(NNZ + 255) / 256, 256, 0, stream>>>(adj_rows, adj_cols, adj_vals, perm, offs,
                                                  cursor, cols_s, colsp_s, vals_s, dflag, NNZ);
    // agg segment CSR
    count_k<<<(N + 255) / 256, 256, 0, stream>>>(agg_rows, scnt, N);
    scan_local_k<<<nbscan_s, 1024, 0, stream>>>(scnt, soffs, sbsums, S);
    scan_bsums_k<<<1, 64, 0, stream>>>(sbsums, nbscan_s);
    scan_add_k<<<(S + 255) / 256, 256, 0, stream>>>(soffs, sbsums, S, N);
    fill_s_k<<<(N + 255) / 256, 256, 0, stream>>>(agg_rows, agg_vals, soffs, scursor, sidx, sval,
                                                  dflag, N);

    const int MT = (N + 127) / 128;
    const int SPB = (N + 3) / 4;  // spmmv blocks (4 rows each)
    // h0 = leaky(x @ mlp_W + b, 0.1)  [MFMA]
    mgemm_k<0, 1, 0><<<dim3(MT, (HID + 127) / 128), 256, 0, stream>>>(x, mlpWt, mlp_b, h0_bf,
                                                                      nullptr, dflag, N, F_IN, HID);
    // BatchNorm
    bn_stats_k<<<(N + 127) / 128, HID, 0, stream>>>(h0_bf, bn_sum, bn_sumsq, N, 128);
    bn_final_k<<<1, HID, 0, stream>>>(bn_sum, bn_sumsq, bn_gamma, bn_beta, bn_scale, bn_shift,
                                      dflag, N);
    bn_apply_k<<<N, HID, 0, stream>>>(h0_bf, bn_scale, bn_shift);

    // HGNN layer 1
    mgemm_k<1, 0, 0><<<dim3(MT, (HID + 127) / 128), 256, 0, stream>>>(h0_bf, hgW1t, hg_b1, zA_bf,
                                                                      nullptr, dflag, N, HID, HID);
    spmmv_k<3, false><<<SPB, 256, 0, stream>>>(offs, cols_s, colsp_s, vals_s, hg_prelu, dflag,
                                               zA_bf, zB_bf, nullptr, N, HID);
    // HGNN layer 2
    mgemm_k<1, 0, 0><<<dim3(MT, (HID + 127) / 128), 256, 0, stream>>>(zB_bf, hgW2t, hg_b2, zA_bf,
                                                                      nullptr, dflag, N, HID, HID);
    spmmv_k<2, false><<<SPB, 256, 0, stream>>>(offs, cols_s, colsp_s, vals_s, nullptr, dflag,
                                               zA_bf, zB_bf, nullptr, N, HID);

    // x_prime -> d_out[1:] (flag dtype) + aligned bf16 copy
    mgemm_k<1, 2, 1><<<dim3(MT, (OUT + 127) / 128), 256, 0, stream>>>(zB_bf, predWt, pred_b, d_out,
                                                                      xp_ws, dflag, N, HID, OUT);
    // fused agg segment-sum + MSE
    aggmse_k<<<(S + 3) / 4, 256, 0, stream>>>(soffs, sidx, sval, xp_ws, y, dflag, lacc, S, OUT);

    // DGI: z = h0 @ dgi_W + b ; dual spmm -> h1 (direct), h2 (perm)
    mgemm_k<1, 0, 0><<<dim3(MT, (OUT + 127) / 128), 256, 0, stream>>>(h0_bf, dgiWt, dgi_b, zA_bf,
                                                                      nullptr, dflag, N, HID, OUT);
    spmmv_k<3, true><<<SPB, 256, 0, stream>>>(offs, cols_s, colsp_s, vals_s, dgi_prelu, dflag,
                                              zA_bf, zB_bf, h2_bf, N, OUT);
    colsum_k<<<(N + 127) / 128, 320, 0, stream>>>(zB_bf, c_acc, N, OUT, 128);
    cfinal_k<<<1, 320, 0, stream>>>(c_acc, c_vec, cnorm, N, OUT);
    cos_k<0><<<256, 256, 0, stream>>>(zB_bf, c_vec, cnorm, &lacc[1], N, OUT);
    cos_k<1><<<256, 256, 0, stream>>>(h2_bf, c_vec, cnorm, &lacc[2], N, OUT);

    final_k<<<1, 64, 0, stream>>>(lacc, d_out, dflag, S * OUT, N);
}